// Round 9
// baseline (6873.322 us; speedup 1.0000x reference)
//
#include <hip/hip_runtime.h>

// ---------------------------------------------------------------------------
// ComNet: R=16 runs x T=512 steps x 32 agents, sequential agent scan.
//   k0: repack W1[:, :93] -> w1T4 [24][64][4]
//   k1: pre1[rti][h] = SC*(b1[h] + xs . W1xs)  (reg-blocked, 4 rti/wave)
//   k2: sequential kernel, 8 blocks x 1 wave, TWO runs per wave (R15).
//   k3: out_kernel: o0/o1 from spilled h2.
// R10: exp2-fold + butterfly + h2 spill: 5049->3819us seq.
// R11: split-K W2 dot + pre1 reg-block: ~null -> broadcast latency (not
//   read count) is the cost; total-seq gap is launch overhead.
// R14: A2/B2 cols in regs, r1-broadcast fold, full unroll: 3330us seq.
// R15: TWO RUNS PER WAVE, half-step skew (FRONT(A,i); BACK(B,i-1);
//   FRONT(B,i); BACK(A,i)). Each run's LDS round trip (the ~40% of the
//   step the wave idles on) is covered by the other run's compute. The
//   skew matters: GCN issue is in-order, so identical-phase interleave
//   would stall both at the same waitcnt. Per-run math order unchanged.
// ---------------------------------------------------------------------------

#define R_RUNS 16
#define T_STEPS 512
#define NA 32
#define HID 64
#define XS 93                       // (NA-1)*3
#define DIN 124
#define STEPS_PER_RUN (T_STEPS * NA)        // 16384
#define RTI_TOT (R_RUNS * STEPS_PER_RUN)    // 262144

#define PRE1_OFF 65536
#define WS_NEEDED ((size_t)PRE1_OFF + (size_t)RTI_TOT * HID * 4 + 4096)

typedef _Float16 half2_t __attribute__((ext_vector_type(2)));
typedef unsigned int uint2v __attribute__((ext_vector_type(2)));

#if defined(__has_builtin)
#if __has_builtin(__builtin_amdgcn_permlane16_swap) && __has_builtin(__builtin_amdgcn_permlane32_swap)
#define HAVE_PLSWAP 1
#endif
#endif
#ifndef HAVE_PLSWAP
#define HAVE_PLSWAP 0
#endif

#if defined(__has_builtin)
#if __has_builtin(__builtin_amdgcn_exp2f)
#define EXPFN(x) __builtin_amdgcn_exp2f(x)
#define SC 2.8853900817779268f      // 2*log2(e): exp(2x) = exp2(SC*x)
#define HAVE_EXP2 1
#endif
#endif
#ifndef HAVE_EXP2
#define EXPFN(x) __expf(x)
#define SC 2.0f
#define HAVE_EXP2 0
#endif

__device__ __forceinline__ float fast_tanh(float x) {
  float e = __expf(2.f * x);
  return fmaf(-2.f, __builtin_amdgcn_rcpf(e + 1.f), 1.f);
}

__device__ __forceinline__ float dot2h(half2_t a, half2_t b, float c) {
#if __has_builtin(__builtin_amdgcn_fdot2)
  return __builtin_amdgcn_fdot2(a, b, c, false);
#else
  return fmaf((float)a.x, (float)b.x, fmaf((float)a.y, (float)b.y, c));
#endif
}

__device__ __forceinline__ half2_t bch(unsigned u) {
  return __builtin_bit_cast(half2_t, u);
}

#define DPP_ADD(x, ctrl, rmask) \
  (x) += __int_as_float(__builtin_amdgcn_update_dpp(0, __float_as_int(x), (ctrl), (rmask), 0xf, true))

// legacy shr-tree reduce (used by seq_fused)
__device__ __forceinline__ float wave64_sum_bcast(float x) {
  DPP_ADD(x, 0x111, 0xf);
  DPP_ADD(x, 0x112, 0xf);
  DPP_ADD(x, 0x114, 0xf);
  DPP_ADD(x, 0x118, 0xf);
  DPP_ADD(x, 0x142, 0xa);
  DPP_ADD(x, 0x143, 0xc);
  return __int_as_float(__builtin_amdgcn_readlane(__float_as_int(x), 63));
}

// all-lanes butterfly sum
__device__ __forceinline__ float wave64_sum_all(float x) {
  DPP_ADD(x, 0xB1, 0xf);
  DPP_ADD(x, 0x4E, 0xf);
  DPP_ADD(x, 0x141, 0xf);
  DPP_ADD(x, 0x140, 0xf);
#if HAVE_PLSWAP
  uint2v p = __builtin_amdgcn_permlane16_swap(__float_as_uint(x), __float_as_uint(x), false, false);
  x = __uint_as_float(p[0]) + __uint_as_float(p[1]);
  p = __builtin_amdgcn_permlane32_swap(__float_as_uint(x), __float_as_uint(x), false, false);
  x = __uint_as_float(p[0]) + __uint_as_float(p[1]);
  return x;
#else
  DPP_ADD(x, 0x142, 0xa);
  DPP_ADD(x, 0x143, 0xc);
  return __int_as_float(__builtin_amdgcn_readlane(__float_as_int(x), 63));
#endif
}

// ---------------- k0: repack W1 xs-part -> [24][64][4], zero-padded --------
__global__ void transpose_w1(const float* __restrict__ w1, float* __restrict__ w1T4) {
  int idx = blockIdx.x * blockDim.x + threadIdx.x;
  if (idx < 24 * HID * 4) {
    int c = idx & 3, h = (idx >> 2) & 63, kk = idx >> 8;
    int k = 4 * kk + c;
    w1T4[idx] = (k < XS) ? w1[h * DIN + k] : 0.f;
  }
}

// ---------------- k1: pre1 = SC * (b1 + xs @ W1xs^T), reg-blocked ----------
#define PRE1_BATCH 4
__global__ __launch_bounds__(256) void pre1_kernel(
    const float* __restrict__ runs, const float* __restrict__ w1T4,
    const float* __restrict__ b1, float* __restrict__ pre1) {
  const int wid = (blockIdx.x * 256 + threadIdx.x) >> 6;
  const int lane = threadIdx.x & 63;
  const int rti0 = wid * PRE1_BATCH;
  const float4* wv = (const float4*)w1T4;
  float4 w[24];
#pragma unroll
  for (int kk = 0; kk < 24; ++kk) w[kk] = wv[kk * 64 + lane];
  const float b1s = b1[lane];
#pragma unroll
  for (int u = 0; u < PRE1_BATCH; ++u) {
    const float* xs = runs + (size_t)(rti0 + u) * XS;
    float a0 = b1s, a1 = 0.f, a2 = 0.f, a3 = 0.f;
#pragma unroll
    for (int kk = 0; kk < 23; ++kk) {
      a0 = fmaf(xs[4 * kk + 0], w[kk].x, a0);
      a1 = fmaf(xs[4 * kk + 1], w[kk].y, a1);
      a2 = fmaf(xs[4 * kk + 2], w[kk].z, a2);
      a3 = fmaf(xs[4 * kk + 3], w[kk].w, a3);
    }
    a0 = fmaf(xs[92], w[23].x, a0);
    pre1[(size_t)(rti0 + u) * HID + lane] = SC * ((a0 + a1) + (a2 + a3));
  }
}

// ---------------- k3: o0/o1 from spilled h2 ----------------
__global__ __launch_bounds__(256) void out_kernel(
    const float* __restrict__ h2, const float* __restrict__ w3,
    const float* __restrict__ b3, float* __restrict__ out) {
  const int rti = blockIdx.x * 256 + threadIdx.x;
  const float4* hv4 = (const float4*)(h2 + (size_t)rti * HID);
  const float4* w0v = (const float4*)w3;
  const float4* w1v = (const float4*)(w3 + HID);
  float p00 = 0.f, p01 = 0.f, p02 = 0.f, p03 = 0.f;
  float p10 = 0.f, p11 = 0.f, p12 = 0.f, p13 = 0.f;
#pragma unroll
  for (int k = 0; k < 16; ++k) {
    float4 hv = hv4[k];
    float4 w0 = w0v[k];
    float4 w1r = w1v[k];
    p00 = fmaf(w0.x, hv.x, p00);  p01 = fmaf(w0.y, hv.y, p01);
    p02 = fmaf(w0.z, hv.z, p02);  p03 = fmaf(w0.w, hv.w, p03);
    p10 = fmaf(w1r.x, hv.x, p10); p11 = fmaf(w1r.y, hv.y, p11);
    p12 = fmaf(w1r.z, hv.z, p12); p13 = fmaf(w1r.w, hv.w, p13);
  }
  float o0 = ((p00 + p01) + (p02 + p03)) + b3[0];
  float o1 = ((p10 + p11) + (p12 + p13)) + b3[1];
  *(float2*)(out + (size_t)rti * 2) = make_float2(o0, o1);
}

// ---------------- k2: two runs per wave, half-step skew ----------------
__global__ __launch_bounds__(64, 1) void seq_kernel(
    const float* __restrict__ w1, const float* __restrict__ w2,
    const float* __restrict__ b2, const float* __restrict__ w3,
    const float* __restrict__ b3, const float* __restrict__ comm_init,
    float* pre1h2) {
  const int h = threadIdx.x;
  const int rA = blockIdx.x * 2;
  const int rB = rA + 1;

  __shared__ __align__(16) float commLA[NA];
  __shared__ __align__(16) float commLB[NA];
  __shared__ __align__(16) _Float16 h1sA[HID];
  __shared__ __align__(16) _Float16 h1sB[HID];
  __shared__ __align__(16) float pbuf[2][2][2048 + 64];  // [run][ring][row]

  // ---- A2/B2 columns (time-invariant, shared by both runs) ----
  float A2r[33], B2r[33];
#pragma unroll
  for (int j = 0; j < 31; ++j) A2r[j] = SC * w1[h * DIN + 93 + j];
  A2r[31] = 0.f;
  A2r[32] = 0.f;
  B2r[0] = 0.f;
#pragma unroll
  for (int j = 1; j < 32; ++j) B2r[j] = SC * w1[h * DIN + 92 + j];
  B2r[32] = 0.f;

  const float* wOwn = w2 + h * HID;
  float rsum = 0.f;
#pragma unroll
  for (int k = 0; k < HID; ++k) rsum += wOwn[k];

#if HAVE_PLSWAP
  const int hi = h >> 5;
  const int hi4 = hi * 4;
  const float4* wA = (const float4*)(w2 + h * HID + hi * 32);
  const float4* wB = (const float4*)(w2 + (h ^ 32) * HID + hi * 32);
  const float4 A0 = wA[0], A1 = wA[1], A2v = wA[2], A3 = wA[3];
  const float4 A4 = wA[4], A5 = wA[5], A6 = wA[6], A7 = wA[7];
  const float4 B0 = wB[0], B1 = wB[1], B2v = wB[2], B3 = wB[3];
  const float4 B4 = wB[4], B5 = wB[5], B6 = wB[6], B7 = wB[7];
#define PK2N(n, f4) \
  const half2_t n##a = {(_Float16)(-2.f * SC * (f4).x), (_Float16)(-2.f * SC * (f4).y)}; \
  const half2_t n##b = {(_Float16)(-2.f * SC * (f4).z), (_Float16)(-2.f * SC * (f4).w)}
  PK2N(pa0, A0); PK2N(pa1, A1); PK2N(pa2, A2v); PK2N(pa3, A3);
  PK2N(pa4, A4); PK2N(pa5, A5); PK2N(pa6, A6);  PK2N(pa7, A7);
  PK2N(pb0, B0); PK2N(pb1, B1); PK2N(pb2, B2v); PK2N(pb3, B3);
  PK2N(pb4, B4); PK2N(pb5, B5); PK2N(pb6, B6);  PK2N(pb7, B7);
#undef PK2N
#define DOTP(Xq, e, o) \
      a0 = dot2h(pa##e##a, bch(Xq.x), a0); a2 = dot2h(pb##e##a, bch(Xq.x), a2); \
      a1 = dot2h(pa##e##b, bch(Xq.y), a1); a3 = dot2h(pb##e##b, bch(Xq.y), a3); \
      a0 = dot2h(pa##o##a, bch(Xq.z), a0); a2 = dot2h(pb##o##a, bch(Xq.z), a2); \
      a1 = dot2h(pa##o##b, bch(Xq.w), a1); a3 = dot2h(pb##o##b, bch(Xq.w), a3)
#define DOT_Y2(bufp, Y2OUT) { \
      const uint4* hv_ = (const uint4*)(bufp); \
      uint4 X0 = hv_[hi4 + 0], X1 = hv_[hi4 + 1]; \
      uint4 X2 = hv_[hi4 + 2], X3 = hv_[hi4 + 3]; \
      float a0 = base2, a1 = 0.f, a2 = 0.f, a3 = 0.f; \
      DOTP(X0, 0, 1); DOTP(X1, 2, 3); DOTP(X2, 4, 5); DOTP(X3, 6, 7); \
      float pA_ = a0 + a1, pBo_ = a2 + a3; \
      uint2v sw_ = __builtin_amdgcn_permlane32_swap( \
          __float_as_uint(pBo_), __float_as_uint(pBo_), false, false); \
      Y2OUT = pA_ + (hi ? __uint_as_float(sw_[0]) : __uint_as_float(sw_[1])); }
#else
  const float4* w2v = (const float4*)(w2 + h * HID);
  const float4 r0 = w2v[0],  r1q = w2v[1], r2q = w2v[2],  r3q = w2v[3];
  const float4 r4 = w2v[4],  r5 = w2v[5],  r6 = w2v[6],  r7 = w2v[7];
  const float4 r8 = w2v[8],  r9 = w2v[9],  r10 = w2v[10], r11 = w2v[11];
  const float4 r12 = w2v[12], r13 = w2v[13], r14 = w2v[14], r15 = w2v[15];
#define PK2N(n, f4) \
  const half2_t n##a = {(_Float16)(-2.f * SC * (f4).x), (_Float16)(-2.f * SC * (f4).y)}; \
  const half2_t n##b = {(_Float16)(-2.f * SC * (f4).z), (_Float16)(-2.f * SC * (f4).w)}
  PK2N(q0, r0);  PK2N(q1, r1q); PK2N(q2, r2q); PK2N(q3, r3q);
  PK2N(q4, r4);  PK2N(q5, r5);  PK2N(q6, r6);  PK2N(q7, r7);
  PK2N(q8, r8);  PK2N(q9, r9);  PK2N(q10, r10); PK2N(q11, r11);
  PK2N(q12, r12); PK2N(q13, r13); PK2N(q14, r14); PK2N(q15, r15);
#undef PK2N
#define DOTB(Xq, qe, qo) \
      a0 = dot2h(qe##a, bch(Xq.x), a0); a1 = dot2h(qe##b, bch(Xq.y), a1); \
      a2 = dot2h(qo##a, bch(Xq.z), a2); a3 = dot2h(qo##b, bch(Xq.w), a3)
#define DOT_Y2(bufp, Y2OUT) { \
      const uint4* hv_ = (const uint4*)(bufp); \
      uint4 X0 = hv_[0], X1 = hv_[1], X2 = hv_[2], X3 = hv_[3]; \
      uint4 X4 = hv_[4], X5 = hv_[5], X6 = hv_[6], X7 = hv_[7]; \
      float a0 = base2, a1 = 0.f, a2 = 0.f, a3 = 0.f; \
      DOTB(X0, q0, q1);   DOTB(X1, q2, q3); \
      DOTB(X2, q4, q5);   DOTB(X3, q6, q7); \
      DOTB(X4, q8, q9);   DOTB(X5, q10, q11); \
      DOTB(X6, q12, q13); DOTB(X7, q14, q15); \
      Y2OUT = (a0 + a1) + (a2 + a3); }
#endif

  const float base2 = SC * b2[h] + SC * rsum;
  const float w32h = w3[2 * HID + h];
  const float w32n2 = -2.f * w32h;
  const float b32 = b3[2];

  float commRA = (h < NA) ? comm_init[rA * NA + h] : 0.f;
  float commRB = (h < NA) ? comm_init[rB * NA + h] : 0.f;
  if (h < NA) commLA[h] = commRA;
  if (h < NA) commLB[h] = commRB;

  float* prowA = pre1h2 + (size_t)rA * STEPS_PER_RUN * HID;
  float* prowB = pre1h2 + (size_t)rB * STEPS_PER_RUN * HID;

  // prime rows 0 and 1 for both runs
  {
#pragma unroll
    for (int run = 0; run < 2; ++run) {
      const float* pr = run ? prowB : prowA;
      const float4* s0 = (const float4*)pr;
      const float4* s1 = (const float4*)(pr + 2048);
      float4* d0 = (float4*)&pbuf[run][0][0];
      float4* d1 = (float4*)&pbuf[run][1][0];
#pragma unroll
      for (int j = 0; j < 8; ++j) d0[j * 64 + h] = s0[j * 64 + h];
#pragma unroll
      for (int j = 0; j < 8; ++j) d1[j * 64 + h] = s1[j * 64 + h];
    }
  }

  for (int t = 0; t < T_STEPS; ++t) {
    float* pbA = pbuf[0][t & 1];
    float* pbB = pbuf[1][t & 1];
    int tk = (t + 2 <= T_STEPS - 1) ? t + 2 : T_STEPS - 1;
    const float4* gsA = (const float4*)(prowA + (size_t)tk * 2048);
    const float4* gsB = (const float4*)(prowB + (size_t)tk * 2048);
    float4 gA0 = gsA[0 * 64 + h], gA1 = gsA[1 * 64 + h];
    float4 gA2 = gsA[2 * 64 + h], gA3 = gsA[3 * 64 + h];
    float4 gA4 = gsA[4 * 64 + h], gA5 = gsA[5 * 64 + h];
    float4 gA6 = gsA[6 * 64 + h], gA7 = gsA[7 * 64 + h];
    float4 gB0 = gsB[0 * 64 + h], gB1 = gsB[1 * 64 + h];
    float4 gB2 = gsB[2 * 64 + h], gB3 = gsB[3 * 64 + h];
    float4 gB4 = gsB[4 * 64 + h], gB5 = gsB[5 * 64 + h];
    float4 gB6 = gsB[6 * 64 + h], gB7 = gsB[7 * 64 + h];

    // FB refresh for both runs (amortized over 32 steps)
    float FB2A, FB2B;
    {
      const float4* cv4 = (const float4*)commLA;
      float f0 = 0.f, f1 = 0.f, f2 = 0.f, f3 = 0.f;
#pragma unroll
      for (int q = 0; q < 8; ++q) {
        float4 c = cv4[q];
        f0 = fmaf(B2r[4 * q + 0], c.x, f0);
        f1 = fmaf(B2r[4 * q + 1], c.y, f1);
        f2 = fmaf(B2r[4 * q + 2], c.z, f2);
        f3 = fmaf(B2r[4 * q + 3], c.w, f3);
      }
      FB2A = (f0 + f1) + (f2 + f3);
      const float4* dv4 = (const float4*)commLB;
      float e0 = 0.f, e1 = 0.f, e2 = 0.f, e3 = 0.f;
#pragma unroll
      for (int q = 0; q < 8; ++q) {
        float4 c = dv4[q];
        e0 = fmaf(B2r[4 * q + 0], c.x, e0);
        e1 = fmaf(B2r[4 * q + 1], c.y, e1);
        e2 = fmaf(B2r[4 * q + 2], c.z, e2);
        e3 = fmaf(B2r[4 * q + 3], c.w, e3);
      }
      FB2B = (e0 + e1) + (e2 + e3);
    }
    const float c0sA = commRA;
    const float c0sB = commRB;
    float Q2A = 0.f, S2A = 0.f, Q2B = 0.f, S2B = 0.f;
    float EA = pbA[h] + FB2A;
    float EB = pbB[h] + FB2B;
    float* h2tA = prowA + (size_t)t * 2048;
    float* h2tB = prowB + (size_t)t * 2048;
    float HA, QbA, S2nA;
    float HB, QbB, S2nB;

// FRONT: chain head (exp2/rcp/cvt/ds_write) + off-chain H prep
#define FRONT(P, i) { \
      float e1_ = EXPFN(E##P); \
      float r1_ = __builtin_amdgcn_rcpf(e1_ + 1.f); \
      h1s##P[h] = (_Float16)r1_; \
      float pfn_ = pb##P[((i) + 1) * 64 + h]; \
      float old_ = __int_as_float(__builtin_amdgcn_readlane( \
          __float_as_int(c0s##P), (i) + 1)); \
      S2n##P = fmaf(B2r[(i) + 1], old_, S2##P); \
      Qb##P = fmaf(A2r[(i)], b32, Q2##P); \
      H##P = pfn_ + (FB2##P - S2n##P) + Qb##P; }

// BACK: reads + dots + act2 + butterfly + state update
#define BACK(P, i) { \
      float y2_; \
      DOT_Y2(h1s##P, y2_); \
      float e2_ = EXPFN(y2_); \
      float r2_ = __builtin_amdgcn_rcpf(e2_ + 1.f); \
      float xr_ = fmaf(w32n2, r2_, w32h); \
      float csum_ = wave64_sum_all(xr_); \
      float h2v_ = fmaf(-2.f, r2_, 1.f); \
      h2t##P[(i) * 64 + h] = h2v_; \
      commR##P = (h == (i)) ? csum_ + b32 : commR##P; \
      E##P = fmaf(A2r[(i)], csum_, H##P); \
      Q2##P = fmaf(A2r[(i)], csum_, Qb##P); \
      S2##P = S2n##P; }

    FRONT(A, 0);
    FRONT(B, 0);
    BACK(A, 0);
#pragma unroll
    for (int i = 1; i < NA; ++i) {
      FRONT(A, i);     // A's round trip covered by BACK(B,i-1)+FRONT(B,i)
      BACK(B, i - 1);  // B's data written last iter: long since landed
      FRONT(B, i);     // B's round trip covered by BACK(A,i)+FRONT(A,i+1)
      BACK(A, i);
    }
    BACK(B, NA - 1);
#undef FRONT
#undef BACK

    if (h < NA) commLA[h] = commRA;
    if (h < NA) commLB[h] = commRB;
    float4* pdA = (float4*)pbA;
    pdA[0 * 64 + h] = gA0; pdA[1 * 64 + h] = gA1;
    pdA[2 * 64 + h] = gA2; pdA[3 * 64 + h] = gA3;
    pdA[4 * 64 + h] = gA4; pdA[5 * 64 + h] = gA5;
    pdA[6 * 64 + h] = gA6; pdA[7 * 64 + h] = gA7;
    float4* pdB = (float4*)pbB;
    pdB[0 * 64 + h] = gB0; pdB[1 * 64 + h] = gB1;
    pdB[2 * 64 + h] = gB2; pdB[3 * 64 + h] = gB3;
    pdB[4 * 64 + h] = gB4; pdB[5 * 64 + h] = gB5;
    pdB[6 * 64 + h] = gB6; pdB[7 * 64 + h] = gB7;
  }
}

// ---------------- fallback: fully fused, zero workspace (unused when ws ok) --
__global__ __launch_bounds__(64, 1) void seq_fused(
    const float* __restrict__ runs, const float* __restrict__ comm_init,
    const float* __restrict__ w1, const float* __restrict__ b1,
    const float* __restrict__ w2, const float* __restrict__ b2,
    const float* __restrict__ w3, const float* __restrict__ b3,
    float* __restrict__ out) {
  const int r = blockIdx.x;
  const int h = threadIdx.x;
  const int hb = h * 33;

  __shared__ float Asl[HID * 33];
  __shared__ float Bsl[HID * 33];
  __shared__ float commL[NA];
  __shared__ __align__(16) float h1s[HID];
  __shared__ float w1xs[XS * HID];
  __shared__ __align__(16) float xsl[96];

  for (int j = 0; j < 31; ++j) Asl[hb + j] = w1[h * DIN + 93 + j];
  Asl[hb + 31] = 0.f;
  Bsl[hb] = 0.f;
  for (int j = 1; j < 32; ++j) Bsl[hb + j] = w1[h * DIN + 92 + j];
  for (int k = 0; k < XS; ++k) w1xs[k * HID + h] = w1[h * DIN + k];

  float w2r[HID];
#pragma unroll
  for (int k = 0; k < HID; ++k) w2r[k] = w2[h * HID + k];
  const float b1h = b1[h];
  const float b2h = b2[h];
  const float w30h = w3[h], w31h = w3[HID + h], w32h = w3[2 * HID + h];
  const float b30 = b3[0], b31 = b3[1], b32 = b3[2];
  if (h < NA) commL[h] = comm_init[r * NA + h];

  const float* xbase = runs + (size_t)r * STEPS_PER_RUN * XS;
  float xa = xbase[h];
  float xb = (h < XS - 64) ? xbase[64 + h] : 0.f;
  float* outp = out + (size_t)r * STEPS_PER_RUN * 2;
  __syncthreads();

  int s = 0;
  for (int t = 0; t < T_STEPS; ++t) {
    float FB = 0.f;
#pragma unroll
    for (int j = 0; j < NA; ++j) FB = fmaf(Bsl[hb + j], commL[j], FB);
    float Q = 0.f, S = 0.f;
    for (int i = 0; i < NA; ++i, ++s) {
      int sn = s + 1; if (sn > STEPS_PER_RUN - 1) sn = STEPS_PER_RUN - 1;
      const float* xn = xbase + (size_t)sn * XS;
      xsl[h] = xa;
      if (h < XS - 64) xsl[64 + h] = xb;
      __syncthreads();
      float xa_n = xn[h];
      float xb_n = (h < XS - 64) ? xn[64 + h] : 0.f;
      float a0 = b1h, a1 = 0.f, a2 = 0.f;
#pragma unroll 4
      for (int k = 0; k < 31; ++k) {
        a0 = fmaf(xsl[3 * k],     w1xs[(3 * k) * HID + h],     a0);
        a1 = fmaf(xsl[3 * k + 1], w1xs[(3 * k + 1) * HID + h], a1);
        a2 = fmaf(xsl[3 * k + 2], w1xs[(3 * k + 2) * HID + h], a2);
      }
      float old_i = commL[i];
      S = fmaf(Bsl[hb + i], old_i, S);
      float h1 = fast_tanh(((a0 + a1) + a2) + FB + Q - S);
      h1s[h] = h1;
      __syncthreads();
      float c0 = b2h, c1 = 0.f, c2 = 0.f, c3 = 0.f;
      const float4* hv4 = (const float4*)h1s;
#pragma unroll
      for (int k4 = 0; k4 < 16; ++k4) {
        float4 hv = hv4[k4];
        c0 = fmaf(w2r[4 * k4 + 0], hv.x, c0);
        c1 = fmaf(w2r[4 * k4 + 1], hv.y, c1);
        c2 = fmaf(w2r[4 * k4 + 2], hv.z, c2);
        c3 = fmaf(w2r[4 * k4 + 3], hv.w, c3);
      }
      float h2 = fast_tanh((c0 + c1) + (c2 + c3));
      float o0 = wave64_sum_bcast(w30h * h2) + b30;
      float o1 = wave64_sum_bcast(w31h * h2) + b31;
      float c_new = wave64_sum_bcast(w32h * h2) + b32;
      if (h == 0) *(float2*)(outp + (size_t)s * 2) = make_float2(o0, o1);
      Q = fmaf(Asl[hb + i], c_new, Q);
      if (h == i) commL[h] = c_new;
      __syncthreads();
      xa = xa_n; xb = xb_n;
    }
  }
}

extern "C" void kernel_launch(void* const* d_in, const int* in_sizes, int n_in,
                              void* d_out, int out_size, void* d_ws, size_t ws_size,
                              hipStream_t stream) {
  const float* runs = (const float*)d_in[0];
  const float* comm_init = (const float*)d_in[1];
  const float* w1 = (const float*)d_in[2];
  const float* b1 = (const float*)d_in[3];
  const float* w2 = (const float*)d_in[4];
  const float* b2 = (const float*)d_in[5];
  const float* w3 = (const float*)d_in[6];
  const float* b3 = (const float*)d_in[7];
  float* out = (float*)d_out;

  if (ws_size >= WS_NEEDED) {
    float* w1T4 = (float*)d_ws;
    float* pre1 = (float*)((char*)d_ws + PRE1_OFF);
    hipLaunchKernelGGL(transpose_w1, dim3((24 * HID * 4 + 255) / 256), dim3(256), 0, stream,
                       w1, w1T4);
    hipLaunchKernelGGL(pre1_kernel, dim3(RTI_TOT / (PRE1_BATCH * 4)), dim3(256), 0, stream,
                       runs, w1T4, b1, pre1);
    hipLaunchKernelGGL(seq_kernel, dim3(R_RUNS / 2), dim3(64), 0, stream,
                       w1, w2, b2, w3, b3, comm_init, pre1);
    hipLaunchKernelGGL(out_kernel, dim3(RTI_TOT / 256), dim3(256), 0, stream,
                       pre1, w3, b3, out);
  } else {
    hipLaunchKernelGGL(seq_fused, dim3(R_RUNS), dim3(64), 0, stream,
                       runs, comm_init, w1, b1, w2, b2, w3, b3, out);
  }
}

// Round 10
// 6657.796 us; speedup vs baseline: 1.0324x; 1.0324x over previous
//
#include <hip/hip_runtime.h>

// ---------------------------------------------------------------------------
// ComNet: R=16 runs x T=512 steps x 32 agents, sequential agent scan.
//   k0: repack W1[:, :93] -> w1T4;  k1: pre1 (reg-blocked);
//   k2: sequential kernel, 8 blocks x 1 wave, TWO runs per wave;
//   k3: out_kernel from spilled h2.
// R14: A2/B2 regs, r1-broadcast fold, full unroll: 3330us seq (16 blocks).
// R15: FRONT/BACK pair skew: ZERO overlap (930 cyc pair-step = 2x487).
//   Diagnosis: BACK issued ds_reads adjacent to the dots -> read latency
//   fully exposed; in-order wave can't fill a stall with later-program-order
//   work from the other run.
// R16: read/consume split. Per i: W(A)->R(A)->C(B,i-1)->W(B)->R(B)->C(A).
//   R() loads 4 ds_read_b128 into NAMED uint4 locals; C() consumes them one
//   other-chain C+W+R later (~190 cyc of independent issue > ~150 cyc read
//   latency). Per-run op order unchanged -> bit-identical output.
// ---------------------------------------------------------------------------

#define R_RUNS 16
#define T_STEPS 512
#define NA 32
#define HID 64
#define XS 93
#define DIN 124
#define STEPS_PER_RUN (T_STEPS * NA)        // 16384
#define RTI_TOT (R_RUNS * STEPS_PER_RUN)    // 262144

#define PRE1_OFF 65536
#define WS_NEEDED ((size_t)PRE1_OFF + (size_t)RTI_TOT * HID * 4 + 4096)

typedef _Float16 half2_t __attribute__((ext_vector_type(2)));
typedef unsigned int uint2v __attribute__((ext_vector_type(2)));

#if defined(__has_builtin)
#if __has_builtin(__builtin_amdgcn_permlane16_swap) && __has_builtin(__builtin_amdgcn_permlane32_swap)
#define HAVE_PLSWAP 1
#endif
#endif
#ifndef HAVE_PLSWAP
#define HAVE_PLSWAP 0
#endif

#if defined(__has_builtin)
#if __has_builtin(__builtin_amdgcn_exp2f)
#define EXPFN(x) __builtin_amdgcn_exp2f(x)
#define SC 2.8853900817779268f      // 2*log2(e): exp(2x) = exp2(SC*x)
#define HAVE_EXP2 1
#endif
#endif
#ifndef HAVE_EXP2
#define EXPFN(x) __expf(x)
#define SC 2.0f
#define HAVE_EXP2 0
#endif

__device__ __forceinline__ float fast_tanh(float x) {
  float e = __expf(2.f * x);
  return fmaf(-2.f, __builtin_amdgcn_rcpf(e + 1.f), 1.f);
}

__device__ __forceinline__ float dot2h(half2_t a, half2_t b, float c) {
#if __has_builtin(__builtin_amdgcn_fdot2)
  return __builtin_amdgcn_fdot2(a, b, c, false);
#else
  return fmaf((float)a.x, (float)b.x, fmaf((float)a.y, (float)b.y, c));
#endif
}

__device__ __forceinline__ half2_t bch(unsigned u) {
  return __builtin_bit_cast(half2_t, u);
}

#define DPP_ADD(x, ctrl, rmask) \
  (x) += __int_as_float(__builtin_amdgcn_update_dpp(0, __float_as_int(x), (ctrl), (rmask), 0xf, true))

// legacy shr-tree reduce (used by seq_fused)
__device__ __forceinline__ float wave64_sum_bcast(float x) {
  DPP_ADD(x, 0x111, 0xf);
  DPP_ADD(x, 0x112, 0xf);
  DPP_ADD(x, 0x114, 0xf);
  DPP_ADD(x, 0x118, 0xf);
  DPP_ADD(x, 0x142, 0xa);
  DPP_ADD(x, 0x143, 0xc);
  return __int_as_float(__builtin_amdgcn_readlane(__float_as_int(x), 63));
}

// all-lanes butterfly sum
__device__ __forceinline__ float wave64_sum_all(float x) {
  DPP_ADD(x, 0xB1, 0xf);
  DPP_ADD(x, 0x4E, 0xf);
  DPP_ADD(x, 0x141, 0xf);
  DPP_ADD(x, 0x140, 0xf);
#if HAVE_PLSWAP
  uint2v p = __builtin_amdgcn_permlane16_swap(__float_as_uint(x), __float_as_uint(x), false, false);
  x = __uint_as_float(p[0]) + __uint_as_float(p[1]);
  p = __builtin_amdgcn_permlane32_swap(__float_as_uint(x), __float_as_uint(x), false, false);
  x = __uint_as_float(p[0]) + __uint_as_float(p[1]);
  return x;
#else
  DPP_ADD(x, 0x142, 0xa);
  DPP_ADD(x, 0x143, 0xc);
  return __int_as_float(__builtin_amdgcn_readlane(__float_as_int(x), 63));
#endif
}

// ---------------- k0: repack W1 xs-part -> [24][64][4], zero-padded --------
__global__ void transpose_w1(const float* __restrict__ w1, float* __restrict__ w1T4) {
  int idx = blockIdx.x * blockDim.x + threadIdx.x;
  if (idx < 24 * HID * 4) {
    int c = idx & 3, h = (idx >> 2) & 63, kk = idx >> 8;
    int k = 4 * kk + c;
    w1T4[idx] = (k < XS) ? w1[h * DIN + k] : 0.f;
  }
}

// ---------------- k1: pre1 = SC * (b1 + xs @ W1xs^T), reg-blocked ----------
#define PRE1_BATCH 4
__global__ __launch_bounds__(256) void pre1_kernel(
    const float* __restrict__ runs, const float* __restrict__ w1T4,
    const float* __restrict__ b1, float* __restrict__ pre1) {
  const int wid = (blockIdx.x * 256 + threadIdx.x) >> 6;
  const int lane = threadIdx.x & 63;
  const int rti0 = wid * PRE1_BATCH;
  const float4* wv = (const float4*)w1T4;
  float4 w[24];
#pragma unroll
  for (int kk = 0; kk < 24; ++kk) w[kk] = wv[kk * 64 + lane];
  const float b1s = b1[lane];
#pragma unroll
  for (int u = 0; u < PRE1_BATCH; ++u) {
    const float* xs = runs + (size_t)(rti0 + u) * XS;
    float a0 = b1s, a1 = 0.f, a2 = 0.f, a3 = 0.f;
#pragma unroll
    for (int kk = 0; kk < 23; ++kk) {
      a0 = fmaf(xs[4 * kk + 0], w[kk].x, a0);
      a1 = fmaf(xs[4 * kk + 1], w[kk].y, a1);
      a2 = fmaf(xs[4 * kk + 2], w[kk].z, a2);
      a3 = fmaf(xs[4 * kk + 3], w[kk].w, a3);
    }
    a0 = fmaf(xs[92], w[23].x, a0);
    pre1[(size_t)(rti0 + u) * HID + lane] = SC * ((a0 + a1) + (a2 + a3));
  }
}

// ---------------- k3: o0/o1 from spilled h2 ----------------
__global__ __launch_bounds__(256) void out_kernel(
    const float* __restrict__ h2, const float* __restrict__ w3,
    const float* __restrict__ b3, float* __restrict__ out) {
  const int rti = blockIdx.x * 256 + threadIdx.x;
  const float4* hv4 = (const float4*)(h2 + (size_t)rti * HID);
  const float4* w0v = (const float4*)w3;
  const float4* w1v = (const float4*)(w3 + HID);
  float p00 = 0.f, p01 = 0.f, p02 = 0.f, p03 = 0.f;
  float p10 = 0.f, p11 = 0.f, p12 = 0.f, p13 = 0.f;
#pragma unroll
  for (int k = 0; k < 16; ++k) {
    float4 hv = hv4[k];
    float4 w0 = w0v[k];
    float4 w1r = w1v[k];
    p00 = fmaf(w0.x, hv.x, p00);  p01 = fmaf(w0.y, hv.y, p01);
    p02 = fmaf(w0.z, hv.z, p02);  p03 = fmaf(w0.w, hv.w, p03);
    p10 = fmaf(w1r.x, hv.x, p10); p11 = fmaf(w1r.y, hv.y, p11);
    p12 = fmaf(w1r.z, hv.z, p12); p13 = fmaf(w1r.w, hv.w, p13);
  }
  float o0 = ((p00 + p01) + (p02 + p03)) + b3[0];
  float o1 = ((p10 + p11) + (p12 + p13)) + b3[1];
  *(float2*)(out + (size_t)rti * 2) = make_float2(o0, o1);
}

// ---------------- k2: two runs per wave, read/consume-split pipeline -------
__global__ __launch_bounds__(64, 1) void seq_kernel(
    const float* __restrict__ w1, const float* __restrict__ w2,
    const float* __restrict__ b2, const float* __restrict__ w3,
    const float* __restrict__ b3, const float* __restrict__ comm_init,
    float* pre1h2) {
  const int h = threadIdx.x;
  const int rA = blockIdx.x * 2;
  const int rB = rA + 1;

  __shared__ __align__(16) float commLA[NA];
  __shared__ __align__(16) float commLB[NA];
  __shared__ __align__(16) _Float16 h1sA[HID];
  __shared__ __align__(16) _Float16 h1sB[HID];
  __shared__ __align__(16) float pbuf[2][2][2048 + 64];  // [run][ring][row]

  float A2r[33], B2r[33];
#pragma unroll
  for (int j = 0; j < 31; ++j) A2r[j] = SC * w1[h * DIN + 93 + j];
  A2r[31] = 0.f;
  A2r[32] = 0.f;
  B2r[0] = 0.f;
#pragma unroll
  for (int j = 1; j < 32; ++j) B2r[j] = SC * w1[h * DIN + 92 + j];
  B2r[32] = 0.f;

  const float* wOwn = w2 + h * HID;
  float rsum = 0.f;
#pragma unroll
  for (int k = 0; k < HID; ++k) rsum += wOwn[k];

#if HAVE_PLSWAP
  const int hi = h >> 5;
  const int hi4 = hi * 4;
  const float4* wA = (const float4*)(w2 + h * HID + hi * 32);
  const float4* wB = (const float4*)(w2 + (h ^ 32) * HID + hi * 32);
  const float4 A0 = wA[0], A1 = wA[1], A2v = wA[2], A3 = wA[3];
  const float4 A4 = wA[4], A5 = wA[5], A6 = wA[6], A7 = wA[7];
  const float4 B0 = wB[0], B1 = wB[1], B2v = wB[2], B3 = wB[3];
  const float4 B4 = wB[4], B5 = wB[5], B6 = wB[6], B7 = wB[7];
#define PK2N(n, f4) \
  const half2_t n##a = {(_Float16)(-2.f * SC * (f4).x), (_Float16)(-2.f * SC * (f4).y)}; \
  const half2_t n##b = {(_Float16)(-2.f * SC * (f4).z), (_Float16)(-2.f * SC * (f4).w)}
  PK2N(pa0, A0); PK2N(pa1, A1); PK2N(pa2, A2v); PK2N(pa3, A3);
  PK2N(pa4, A4); PK2N(pa5, A5); PK2N(pa6, A6);  PK2N(pa7, A7);
  PK2N(pb0, B0); PK2N(pb1, B1); PK2N(pb2, B2v); PK2N(pb3, B3);
  PK2N(pb4, B4); PK2N(pb5, B5); PK2N(pb6, B6);  PK2N(pb7, B7);
#undef PK2N
#define DOTP(Xq, e, o) \
      a0 = dot2h(pa##e##a, bch(Xq.x), a0); a2 = dot2h(pb##e##a, bch(Xq.x), a2); \
      a1 = dot2h(pa##e##b, bch(Xq.y), a1); a3 = dot2h(pb##e##b, bch(Xq.y), a3); \
      a0 = dot2h(pa##o##a, bch(Xq.z), a0); a2 = dot2h(pb##o##a, bch(Xq.z), a2); \
      a1 = dot2h(pa##o##b, bch(Xq.w), a1); a3 = dot2h(pb##o##b, bch(Xq.w), a3)
// R_: issue the 4 ds_read_b128 into named locals (no consumption here)
#define R_(P) { \
      const uint4* hv_ = (const uint4*)h1s##P; \
      X##P##0 = hv_[hi4 + 0]; X##P##1 = hv_[hi4 + 1]; \
      X##P##2 = hv_[hi4 + 2]; X##P##3 = hv_[hi4 + 3]; }
#define DOTS_Y2(P, Y2OUT) { \
      float a0 = base2, a1 = 0.f, a2 = 0.f, a3 = 0.f; \
      DOTP(X##P##0, 0, 1); DOTP(X##P##1, 2, 3); \
      DOTP(X##P##2, 4, 5); DOTP(X##P##3, 6, 7); \
      float pA_ = a0 + a1, pBo_ = a2 + a3; \
      uint2v sw_ = __builtin_amdgcn_permlane32_swap( \
          __float_as_uint(pBo_), __float_as_uint(pBo_), false, false); \
      Y2OUT = pA_ + (hi ? __uint_as_float(sw_[0]) : __uint_as_float(sw_[1])); }
#else
#define DOTB(Xq, qe, qo) \
      a0 = dot2h(qe##a, bch(Xq.x), a0); a1 = dot2h(qe##b, bch(Xq.y), a1); \
      a2 = dot2h(qo##a, bch(Xq.z), a2); a3 = dot2h(qo##b, bch(Xq.w), a3)
  const float4* w2v = (const float4*)(w2 + h * HID);
  const float4 r0 = w2v[0],  r1q = w2v[1], r2q = w2v[2],  r3q = w2v[3];
  const float4 r4 = w2v[4],  r5 = w2v[5],  r6 = w2v[6],  r7 = w2v[7];
  const float4 r8 = w2v[8],  r9 = w2v[9],  r10 = w2v[10], r11 = w2v[11];
  const float4 r12 = w2v[12], r13 = w2v[13], r14 = w2v[14], r15 = w2v[15];
#define PK2N(n, f4) \
  const half2_t n##a = {(_Float16)(-2.f * SC * (f4).x), (_Float16)(-2.f * SC * (f4).y)}; \
  const half2_t n##b = {(_Float16)(-2.f * SC * (f4).z), (_Float16)(-2.f * SC * (f4).w)}
  PK2N(q0, r0);  PK2N(q1, r1q); PK2N(q2, r2q); PK2N(q3, r3q);
  PK2N(q4, r4);  PK2N(q5, r5);  PK2N(q6, r6);  PK2N(q7, r7);
  PK2N(q8, r8);  PK2N(q9, r9);  PK2N(q10, r10); PK2N(q11, r11);
  PK2N(q12, r12); PK2N(q13, r13); PK2N(q14, r14); PK2N(q15, r15);
#undef PK2N
#define R_(P) { \
      const uint4* hv_ = (const uint4*)h1s##P; \
      X##P##0 = hv_[0]; X##P##1 = hv_[1]; X##P##2 = hv_[2]; X##P##3 = hv_[3]; \
      X##P##4 = hv_[4]; X##P##5 = hv_[5]; X##P##6 = hv_[6]; X##P##7 = hv_[7]; }
#define DOTS_Y2(P, Y2OUT) { \
      float a0 = base2, a1 = 0.f, a2 = 0.f, a3 = 0.f; \
      DOTB(X##P##0, q0, q1);   DOTB(X##P##1, q2, q3); \
      DOTB(X##P##2, q4, q5);   DOTB(X##P##3, q6, q7); \
      DOTB(X##P##4, q8, q9);   DOTB(X##P##5, q10, q11); \
      DOTB(X##P##6, q12, q13); DOTB(X##P##7, q14, q15); \
      Y2OUT = (a0 + a1) + (a2 + a3); }
#endif

  const float base2 = SC * b2[h] + SC * rsum;
  const float w32h = w3[2 * HID + h];
  const float w32n2 = -2.f * w32h;
  const float b32 = b3[2];

  float commRA = (h < NA) ? comm_init[rA * NA + h] : 0.f;
  float commRB = (h < NA) ? comm_init[rB * NA + h] : 0.f;
  if (h < NA) commLA[h] = commRA;
  if (h < NA) commLB[h] = commRB;

  float* prowA = pre1h2 + (size_t)rA * STEPS_PER_RUN * HID;
  float* prowB = pre1h2 + (size_t)rB * STEPS_PER_RUN * HID;

  {
#pragma unroll
    for (int run = 0; run < 2; ++run) {
      const float* pr = run ? prowB : prowA;
      const float4* s0 = (const float4*)pr;
      const float4* s1 = (const float4*)(pr + 2048);
      float4* d0 = (float4*)&pbuf[run][0][0];
      float4* d1 = (float4*)&pbuf[run][1][0];
#pragma unroll
      for (int j = 0; j < 8; ++j) d0[j * 64 + h] = s0[j * 64 + h];
#pragma unroll
      for (int j = 0; j < 8; ++j) d1[j * 64 + h] = s1[j * 64 + h];
    }
  }

  for (int t = 0; t < T_STEPS; ++t) {
    float* pbA = pbuf[0][t & 1];
    float* pbB = pbuf[1][t & 1];
    int tk = (t + 2 <= T_STEPS - 1) ? t + 2 : T_STEPS - 1;
    const float4* gsA = (const float4*)(prowA + (size_t)tk * 2048);
    const float4* gsB = (const float4*)(prowB + (size_t)tk * 2048);
    float4 gA0 = gsA[0 * 64 + h], gA1 = gsA[1 * 64 + h];
    float4 gA2 = gsA[2 * 64 + h], gA3 = gsA[3 * 64 + h];
    float4 gA4 = gsA[4 * 64 + h], gA5 = gsA[5 * 64 + h];
    float4 gA6 = gsA[6 * 64 + h], gA7 = gsA[7 * 64 + h];
    float4 gB0 = gsB[0 * 64 + h], gB1 = gsB[1 * 64 + h];
    float4 gB2 = gsB[2 * 64 + h], gB3 = gsB[3 * 64 + h];
    float4 gB4 = gsB[4 * 64 + h], gB5 = gsB[5 * 64 + h];
    float4 gB6 = gsB[6 * 64 + h], gB7 = gsB[7 * 64 + h];

    float FB2A, FB2B;
    {
      const float4* cv4 = (const float4*)commLA;
      float f0 = 0.f, f1 = 0.f, f2 = 0.f, f3 = 0.f;
#pragma unroll
      for (int q = 0; q < 8; ++q) {
        float4 c = cv4[q];
        f0 = fmaf(B2r[4 * q + 0], c.x, f0);
        f1 = fmaf(B2r[4 * q + 1], c.y, f1);
        f2 = fmaf(B2r[4 * q + 2], c.z, f2);
        f3 = fmaf(B2r[4 * q + 3], c.w, f3);
      }
      FB2A = (f0 + f1) + (f2 + f3);
      const float4* dv4 = (const float4*)commLB;
      float e0 = 0.f, e1 = 0.f, e2 = 0.f, e3 = 0.f;
#pragma unroll
      for (int q = 0; q < 8; ++q) {
        float4 c = dv4[q];
        e0 = fmaf(B2r[4 * q + 0], c.x, e0);
        e1 = fmaf(B2r[4 * q + 1], c.y, e1);
        e2 = fmaf(B2r[4 * q + 2], c.z, e2);
        e3 = fmaf(B2r[4 * q + 3], c.w, e3);
      }
      FB2B = (e0 + e1) + (e2 + e3);
    }
    const float c0sA = commRA;
    const float c0sB = commRB;
    float Q2A = 0.f, S2A = 0.f, Q2B = 0.f, S2B = 0.f;
    float EA = pbA[h] + FB2A;
    float EB = pbB[h] + FB2B;
    float* h2tA = prowA + (size_t)t * 2048;
    float* h2tB = prowB + (size_t)t * 2048;
    float HA, QbA, S2nA;
    float HB, QbB, S2nB;
    uint4 XA0, XA1, XA2, XA3;
    uint4 XB0, XB1, XB2, XB3;
#if !HAVE_PLSWAP
    uint4 XA4, XA5, XA6, XA7;
    uint4 XB4, XB5, XB6, XB7;
#endif

// W_: chain head (exp2/rcp/cvt/ds_write) + off-chain H prep for step i
#define W_(P, i) { \
      float e1_ = EXPFN(E##P); \
      float r1_ = __builtin_amdgcn_rcpf(e1_ + 1.f); \
      h1s##P[h] = (_Float16)r1_; \
      float pfn_ = pb##P[((i) + 1) * 64 + h]; \
      float old_ = __int_as_float(__builtin_amdgcn_readlane( \
          __float_as_int(c0s##P), (i) + 1)); \
      S2n##P = fmaf(B2r[(i) + 1], old_, S2##P); \
      Qb##P = fmaf(A2r[(i)], b32, Q2##P); \
      H##P = pfn_ + (FB2##P - S2n##P) + Qb##P; }

// C_: consume X regs (loaded by R_ one half-pipeline earlier) + state update
#define C_(P, i) { \
      float y2_; \
      DOTS_Y2(P, y2_); \
      float e2_ = EXPFN(y2_); \
      float r2_ = __builtin_amdgcn_rcpf(e2_ + 1.f); \
      float xr_ = fmaf(w32n2, r2_, w32h); \
      float csum_ = wave64_sum_all(xr_); \
      float h2v_ = fmaf(-2.f, r2_, 1.f); \
      h2t##P[(i) * 64 + h] = h2v_; \
      commR##P = (h == (i)) ? csum_ + b32 : commR##P; \
      E##P = fmaf(A2r[(i)], csum_, H##P); \
      Q2##P = fmaf(A2r[(i)], csum_, Qb##P); \
      S2##P = S2n##P; }

    // prologue
    W_(A, 0); R_(A);
    W_(B, 0); R_(B);
    C_(A, 0);              // XA covered by W(B)+R(B)
#pragma unroll
    for (int i = 1; i < NA; ++i) {
      W_(A, i);            // EA from C_(A,i-1): fma-latency only
      R_(A);               // A reads issue; consumed at C_(A,i) below
      C_(B, i - 1);        // XB loaded last iter: ~190 cyc of cover since
      W_(B, i);            // EB from C_(B,i-1): adjacent
      R_(B);               // B reads issue; consumed next iter
      C_(A, i);            // XA covered by C_(B)+W_(B)+R_(B)
    }
    C_(B, NA - 1);         // epilogue: XB from last R_(B)
#undef W_
#undef C_

    if (h < NA) commLA[h] = commRA;
    if (h < NA) commLB[h] = commRB;
    float4* pdA = (float4*)pbA;
    pdA[0 * 64 + h] = gA0; pdA[1 * 64 + h] = gA1;
    pdA[2 * 64 + h] = gA2; pdA[3 * 64 + h] = gA3;
    pdA[4 * 64 + h] = gA4; pdA[5 * 64 + h] = gA5;
    pdA[6 * 64 + h] = gA6; pdA[7 * 64 + h] = gA7;
    float4* pdB = (float4*)pbB;
    pdB[0 * 64 + h] = gB0; pdB[1 * 64 + h] = gB1;
    pdB[2 * 64 + h] = gB2; pdB[3 * 64 + h] = gB3;
    pdB[4 * 64 + h] = gB4; pdB[5 * 64 + h] = gB5;
    pdB[6 * 64 + h] = gB6; pdB[7 * 64 + h] = gB7;
  }
}

// ---------------- fallback: fully fused, zero workspace (unused when ws ok) --
__global__ __launch_bounds__(64, 1) void seq_fused(
    const float* __restrict__ runs, const float* __restrict__ comm_init,
    const float* __restrict__ w1, const float* __restrict__ b1,
    const float* __restrict__ w2, const float* __restrict__ b2,
    const float* __restrict__ w3, const float* __restrict__ b3,
    float* __restrict__ out) {
  const int r = blockIdx.x;
  const int h = threadIdx.x;
  const int hb = h * 33;

  __shared__ float Asl[HID * 33];
  __shared__ float Bsl[HID * 33];
  __shared__ float commL[NA];
  __shared__ __align__(16) float h1s[HID];
  __shared__ float w1xs[XS * HID];
  __shared__ __align__(16) float xsl[96];

  for (int j = 0; j < 31; ++j) Asl[hb + j] = w1[h * DIN + 93 + j];
  Asl[hb + 31] = 0.f;
  Bsl[hb] = 0.f;
  for (int j = 1; j < 32; ++j) Bsl[hb + j] = w1[h * DIN + 92 + j];
  for (int k = 0; k < XS; ++k) w1xs[k * HID + h] = w1[h * DIN + k];

  float w2r[HID];
#pragma unroll
  for (int k = 0; k < HID; ++k) w2r[k] = w2[h * HID + k];
  const float b1h = b1[h];
  const float b2h = b2[h];
  const float w30h = w3[h], w31h = w3[HID + h], w32h = w3[2 * HID + h];
  const float b30 = b3[0], b31 = b3[1], b32 = b3[2];
  if (h < NA) commL[h] = comm_init[r * NA + h];

  const float* xbase = runs + (size_t)r * STEPS_PER_RUN * XS;
  float xa = xbase[h];
  float xb = (h < XS - 64) ? xbase[64 + h] : 0.f;
  float* outp = out + (size_t)r * STEPS_PER_RUN * 2;
  __syncthreads();

  int s = 0;
  for (int t = 0; t < T_STEPS; ++t) {
    float FB = 0.f;
#pragma unroll
    for (int j = 0; j < NA; ++j) FB = fmaf(Bsl[hb + j], commL[j], FB);
    float Q = 0.f, S = 0.f;
    for (int i = 0; i < NA; ++i, ++s) {
      int sn = s + 1; if (sn > STEPS_PER_RUN - 1) sn = STEPS_PER_RUN - 1;
      const float* xn = xbase + (size_t)sn * XS;
      xsl[h] = xa;
      if (h < XS - 64) xsl[64 + h] = xb;
      __syncthreads();
      float xa_n = xn[h];
      float xb_n = (h < XS - 64) ? xn[64 + h] : 0.f;
      float a0 = b1h, a1 = 0.f, a2 = 0.f;
#pragma unroll 4
      for (int k = 0; k < 31; ++k) {
        a0 = fmaf(xsl[3 * k],     w1xs[(3 * k) * HID + h],     a0);
        a1 = fmaf(xsl[3 * k + 1], w1xs[(3 * k + 1) * HID + h], a1);
        a2 = fmaf(xsl[3 * k + 2], w1xs[(3 * k + 2) * HID + h], a2);
      }
      float old_i = commL[i];
      S = fmaf(Bsl[hb + i], old_i, S);
      float h1 = fast_tanh(((a0 + a1) + a2) + FB + Q - S);
      h1s[h] = h1;
      __syncthreads();
      float c0 = b2h, c1 = 0.f, c2 = 0.f, c3 = 0.f;
      const float4* hv4 = (const float4*)h1s;
#pragma unroll
      for (int k4 = 0; k4 < 16; ++k4) {
        float4 hv = hv4[k4];
        c0 = fmaf(w2r[4 * k4 + 0], hv.x, c0);
        c1 = fmaf(w2r[4 * k4 + 1], hv.y, c1);
        c2 = fmaf(w2r[4 * k4 + 2], hv.z, c2);
        c3 = fmaf(w2r[4 * k4 + 3], hv.w, c3);
      }
      float h2 = fast_tanh((c0 + c1) + (c2 + c3));
      float o0 = wave64_sum_bcast(w30h * h2) + b30;
      float o1 = wave64_sum_bcast(w31h * h2) + b31;
      float c_new = wave64_sum_bcast(w32h * h2) + b32;
      if (h == 0) *(float2*)(outp + (size_t)s * 2) = make_float2(o0, o1);
      Q = fmaf(Asl[hb + i], c_new, Q);
      if (h == i) commL[h] = c_new;
      __syncthreads();
      xa = xa_n; xb = xb_n;
    }
  }
}

extern "C" void kernel_launch(void* const* d_in, const int* in_sizes, int n_in,
                              void* d_out, int out_size, void* d_ws, size_t ws_size,
                              hipStream_t stream) {
  const float* runs = (const float*)d_in[0];
  const float* comm_init = (const float*)d_in[1];
  const float* w1 = (const float*)d_in[2];
  const float* b1 = (const float*)d_in[3];
  const float* w2 = (const float*)d_in[4];
  const float* b2 = (const float*)d_in[5];
  const float* w3 = (const float*)d_in[6];
  const float* b3 = (const float*)d_in[7];
  float* out = (float*)d_out;

  if (ws_size >= WS_NEEDED) {
    float* w1T4 = (float*)d_ws;
    float* pre1 = (float*)((char*)d_ws + PRE1_OFF);
    hipLaunchKernelGGL(transpose_w1, dim3((24 * HID * 4 + 255) / 256), dim3(256), 0, stream,
                       w1, w1T4);
    hipLaunchKernelGGL(pre1_kernel, dim3(RTI_TOT / (PRE1_BATCH * 4)), dim3(256), 0, stream,
                       runs, w1T4, b1, pre1);
    hipLaunchKernelGGL(seq_kernel, dim3(R_RUNS / 2), dim3(64), 0, stream,
                       w1, w2, b2, w3, b3, comm_init, pre1);
    hipLaunchKernelGGL(out_kernel, dim3(RTI_TOT / 256), dim3(256), 0, stream,
                       pre1, w3, b3, out);
  } else {
    hipLaunchKernelGGL(seq_fused, dim3(R_RUNS), dim3(64), 0, stream,
                       runs, comm_init, w1, b1, w2, b2, w3, b3, out);
  }
}

// Round 11
// 6045.227 us; speedup vs baseline: 1.1370x; 1.1013x over previous
//
#include <hip/hip_runtime.h>

// ---------------------------------------------------------------------------
// ComNet: R=16 runs x T=512 steps x 32 agents, sequential agent scan.
//   k0: repack W1; k1: pre1 (reg-blocked); k2: 8 blocks x 1 wave, TWO runs
//   per wave; k3: out_kernel from spilled h2.
// R14: A2/B2 regs, r1-broadcast fold, full unroll: 3330us seq (16 blocks).
// R15: FRONT/BACK skew: ZERO overlap (930 cyc pair-step).
// R16: read/consume split: STILL zero overlap (900 cyc). Diagnosis now
//   unambiguous: block-granular alternation can't overlap on in-order
//   issue -- C(B)->W(B) adjacency + internally-serial C blocks put both
//   chains' latency chains in SEQUENCE on the program-order critical path.
// R17: same-index STATEMENT-level interleave. Every op duplicated A,B
//   adjacent: dual TRANS heads, dual ds_write, dual X reads (both LDS round
//   trips in flight TOGETHER), dots alternated per-quad, dual act2, dual
//   interleaved butterfly. Stalls per pair halve; latencies overlap.
//   Per-run op order unchanged -> bit-identical output.
// ---------------------------------------------------------------------------

#define R_RUNS 16
#define T_STEPS 512
#define NA 32
#define HID 64
#define XS 93
#define DIN 124
#define STEPS_PER_RUN (T_STEPS * NA)        // 16384
#define RTI_TOT (R_RUNS * STEPS_PER_RUN)    // 262144

#define PRE1_OFF 65536
#define WS_NEEDED ((size_t)PRE1_OFF + (size_t)RTI_TOT * HID * 4 + 4096)

typedef _Float16 half2_t __attribute__((ext_vector_type(2)));
typedef unsigned int uint2v __attribute__((ext_vector_type(2)));

#if defined(__has_builtin)
#if __has_builtin(__builtin_amdgcn_permlane16_swap) && __has_builtin(__builtin_amdgcn_permlane32_swap)
#define HAVE_PLSWAP 1
#endif
#endif
#ifndef HAVE_PLSWAP
#define HAVE_PLSWAP 0
#endif

#if defined(__has_builtin)
#if __has_builtin(__builtin_amdgcn_exp2f)
#define EXPFN(x) __builtin_amdgcn_exp2f(x)
#define SC 2.8853900817779268f      // 2*log2(e): exp(2x) = exp2(SC*x)
#define HAVE_EXP2 1
#endif
#endif
#ifndef HAVE_EXP2
#define EXPFN(x) __expf(x)
#define SC 2.0f
#define HAVE_EXP2 0
#endif

__device__ __forceinline__ float fast_tanh(float x) {
  float e = __expf(2.f * x);
  return fmaf(-2.f, __builtin_amdgcn_rcpf(e + 1.f), 1.f);
}

__device__ __forceinline__ float dot2h(half2_t a, half2_t b, float c) {
#if __has_builtin(__builtin_amdgcn_fdot2)
  return __builtin_amdgcn_fdot2(a, b, c, false);
#else
  return fmaf((float)a.x, (float)b.x, fmaf((float)a.y, (float)b.y, c));
#endif
}

__device__ __forceinline__ half2_t bch(unsigned u) {
  return __builtin_bit_cast(half2_t, u);
}

#define DPP_ADD(x, ctrl, rmask) \
  (x) += __int_as_float(__builtin_amdgcn_update_dpp(0, __float_as_int(x), (ctrl), (rmask), 0xf, true))

// legacy shr-tree reduce (used by seq_fused)
__device__ __forceinline__ float wave64_sum_bcast(float x) {
  DPP_ADD(x, 0x111, 0xf);
  DPP_ADD(x, 0x112, 0xf);
  DPP_ADD(x, 0x114, 0xf);
  DPP_ADD(x, 0x118, 0xf);
  DPP_ADD(x, 0x142, 0xa);
  DPP_ADD(x, 0x143, 0xc);
  return __int_as_float(__builtin_amdgcn_readlane(__float_as_int(x), 63));
}

// DUAL all-lanes butterfly: two independent sums, statement-interleaved so
// each chain's ~6 dependent cross-lane ops overlap with the other's.
// Per-chain op sequence identical to the single version -> bit-identical.
__device__ __forceinline__ void wave64_sum_all2(float& x0, float& x1) {
#define ST2A(ctrl) DPP_ADD(x0, ctrl, 0xf); DPP_ADD(x1, ctrl, 0xf)
  ST2A(0xB1);   // quad_perm [1,0,3,2] : ^1
  ST2A(0x4E);   // quad_perm [2,3,0,1] : ^2
  ST2A(0x141);  // row_half_mirror
  ST2A(0x140);  // row_mirror
#undef ST2A
#if HAVE_PLSWAP
  uint2v p0 = __builtin_amdgcn_permlane16_swap(__float_as_uint(x0), __float_as_uint(x0), false, false);
  uint2v p1 = __builtin_amdgcn_permlane16_swap(__float_as_uint(x1), __float_as_uint(x1), false, false);
  x0 = __uint_as_float(p0[0]) + __uint_as_float(p0[1]);
  x1 = __uint_as_float(p1[0]) + __uint_as_float(p1[1]);
  uint2v q0 = __builtin_amdgcn_permlane32_swap(__float_as_uint(x0), __float_as_uint(x0), false, false);
  uint2v q1 = __builtin_amdgcn_permlane32_swap(__float_as_uint(x1), __float_as_uint(x1), false, false);
  x0 = __uint_as_float(q0[0]) + __uint_as_float(q0[1]);
  x1 = __uint_as_float(q1[0]) + __uint_as_float(q1[1]);
#else
  DPP_ADD(x0, 0x142, 0xa); DPP_ADD(x1, 0x142, 0xa);
  DPP_ADD(x0, 0x143, 0xc); DPP_ADD(x1, 0x143, 0xc);
  x0 = __int_as_float(__builtin_amdgcn_readlane(__float_as_int(x0), 63));
  x1 = __int_as_float(__builtin_amdgcn_readlane(__float_as_int(x1), 63));
#endif
}

// ---------------- k0: repack W1 xs-part -> [24][64][4], zero-padded --------
__global__ void transpose_w1(const float* __restrict__ w1, float* __restrict__ w1T4) {
  int idx = blockIdx.x * blockDim.x + threadIdx.x;
  if (idx < 24 * HID * 4) {
    int c = idx & 3, h = (idx >> 2) & 63, kk = idx >> 8;
    int k = 4 * kk + c;
    w1T4[idx] = (k < XS) ? w1[h * DIN + k] : 0.f;
  }
}

// ---------------- k1: pre1 = SC * (b1 + xs @ W1xs^T), reg-blocked ----------
#define PRE1_BATCH 4
__global__ __launch_bounds__(256) void pre1_kernel(
    const float* __restrict__ runs, const float* __restrict__ w1T4,
    const float* __restrict__ b1, float* __restrict__ pre1) {
  const int wid = (blockIdx.x * 256 + threadIdx.x) >> 6;
  const int lane = threadIdx.x & 63;
  const int rti0 = wid * PRE1_BATCH;
  const float4* wv = (const float4*)w1T4;
  float4 w[24];
#pragma unroll
  for (int kk = 0; kk < 24; ++kk) w[kk] = wv[kk * 64 + lane];
  const float b1s = b1[lane];
#pragma unroll
  for (int u = 0; u < PRE1_BATCH; ++u) {
    const float* xs = runs + (size_t)(rti0 + u) * XS;
    float a0 = b1s, a1 = 0.f, a2 = 0.f, a3 = 0.f;
#pragma unroll
    for (int kk = 0; kk < 23; ++kk) {
      a0 = fmaf(xs[4 * kk + 0], w[kk].x, a0);
      a1 = fmaf(xs[4 * kk + 1], w[kk].y, a1);
      a2 = fmaf(xs[4 * kk + 2], w[kk].z, a2);
      a3 = fmaf(xs[4 * kk + 3], w[kk].w, a3);
    }
    a0 = fmaf(xs[92], w[23].x, a0);
    pre1[(size_t)(rti0 + u) * HID + lane] = SC * ((a0 + a1) + (a2 + a3));
  }
}

// ---------------- k3: o0/o1 from spilled h2 ----------------
__global__ __launch_bounds__(256) void out_kernel(
    const float* __restrict__ h2, const float* __restrict__ w3,
    const float* __restrict__ b3, float* __restrict__ out) {
  const int rti = blockIdx.x * 256 + threadIdx.x;
  const float4* hv4 = (const float4*)(h2 + (size_t)rti * HID);
  const float4* w0v = (const float4*)w3;
  const float4* w1v = (const float4*)(w3 + HID);
  float p00 = 0.f, p01 = 0.f, p02 = 0.f, p03 = 0.f;
  float p10 = 0.f, p11 = 0.f, p12 = 0.f, p13 = 0.f;
#pragma unroll
  for (int k = 0; k < 16; ++k) {
    float4 hv = hv4[k];
    float4 w0 = w0v[k];
    float4 w1r = w1v[k];
    p00 = fmaf(w0.x, hv.x, p00);  p01 = fmaf(w0.y, hv.y, p01);
    p02 = fmaf(w0.z, hv.z, p02);  p03 = fmaf(w0.w, hv.w, p03);
    p10 = fmaf(w1r.x, hv.x, p10); p11 = fmaf(w1r.y, hv.y, p11);
    p12 = fmaf(w1r.z, hv.z, p12); p13 = fmaf(w1r.w, hv.w, p13);
  }
  float o0 = ((p00 + p01) + (p02 + p03)) + b3[0];
  float o1 = ((p10 + p11) + (p12 + p13)) + b3[1];
  *(float2*)(out + (size_t)rti * 2) = make_float2(o0, o1);
}

// ---------------- k2: two runs per wave, statement-interleaved -------------
__global__ __launch_bounds__(64, 1) void seq_kernel(
    const float* __restrict__ w1, const float* __restrict__ w2,
    const float* __restrict__ b2, const float* __restrict__ w3,
    const float* __restrict__ b3, const float* __restrict__ comm_init,
    float* pre1h2) {
  const int h = threadIdx.x;
  const int rA = blockIdx.x * 2;
  const int rB = rA + 1;

  __shared__ __align__(16) float commLA[NA];
  __shared__ __align__(16) float commLB[NA];
  __shared__ __align__(16) _Float16 h1sA[HID];
  __shared__ __align__(16) _Float16 h1sB[HID];
  __shared__ __align__(16) float pbuf[2][2][2048 + 64];  // [run][ring][row]

  float A2r[33], B2r[33];
#pragma unroll
  for (int j = 0; j < 31; ++j) A2r[j] = SC * w1[h * DIN + 93 + j];
  A2r[31] = 0.f;
  A2r[32] = 0.f;
  B2r[0] = 0.f;
#pragma unroll
  for (int j = 1; j < 32; ++j) B2r[j] = SC * w1[h * DIN + 92 + j];
  B2r[32] = 0.f;

  const float* wOwn = w2 + h * HID;
  float rsum = 0.f;
#pragma unroll
  for (int k = 0; k < HID; ++k) rsum += wOwn[k];

#if HAVE_PLSWAP
  const int hi = h >> 5;
  const int hi4 = hi * 4;
  const float4* wA = (const float4*)(w2 + h * HID + hi * 32);
  const float4* wB = (const float4*)(w2 + (h ^ 32) * HID + hi * 32);
  const float4 A0 = wA[0], A1 = wA[1], A2v = wA[2], A3 = wA[3];
  const float4 A4 = wA[4], A5 = wA[5], A6 = wA[6], A7 = wA[7];
  const float4 B0 = wB[0], B1 = wB[1], B2v = wB[2], B3 = wB[3];
  const float4 B4 = wB[4], B5 = wB[5], B6 = wB[6], B7 = wB[7];
#define PK2N(n, f4) \
  const half2_t n##a = {(_Float16)(-2.f * SC * (f4).x), (_Float16)(-2.f * SC * (f4).y)}; \
  const half2_t n##b = {(_Float16)(-2.f * SC * (f4).z), (_Float16)(-2.f * SC * (f4).w)}
  PK2N(pa0, A0); PK2N(pa1, A1); PK2N(pa2, A2v); PK2N(pa3, A3);
  PK2N(pa4, A4); PK2N(pa5, A5); PK2N(pa6, A6);  PK2N(pa7, A7);
  PK2N(pb0, B0); PK2N(pb1, B1); PK2N(pb2, B2v); PK2N(pb3, B3);
  PK2N(pb4, B4); PK2N(pb5, B5); PK2N(pb6, B6);  PK2N(pb7, B7);
#undef PK2N
// one quad of dots for chain P (accumulators aP0..aP3), weight pair (e,o)
#define DOTQ(P, Xq, e, o) \
      a##P##0 = dot2h(pa##e##a, bch(Xq.x), a##P##0); \
      a##P##2 = dot2h(pb##e##a, bch(Xq.x), a##P##2); \
      a##P##1 = dot2h(pa##e##b, bch(Xq.y), a##P##1); \
      a##P##3 = dot2h(pb##e##b, bch(Xq.y), a##P##3); \
      a##P##0 = dot2h(pa##o##a, bch(Xq.z), a##P##0); \
      a##P##2 = dot2h(pb##o##a, bch(Xq.z), a##P##2); \
      a##P##1 = dot2h(pa##o##b, bch(Xq.w), a##P##1); \
      a##P##3 = dot2h(pb##o##b, bch(Xq.w), a##P##3)
#else
  const float4* w2v = (const float4*)(w2 + h * HID);
  const float4 r0 = w2v[0],  r1q = w2v[1], r2q = w2v[2],  r3q = w2v[3];
  const float4 r4 = w2v[4],  r5 = w2v[5],  r6 = w2v[6],  r7 = w2v[7];
  const float4 r8 = w2v[8],  r9 = w2v[9],  r10 = w2v[10], r11 = w2v[11];
  const float4 r12 = w2v[12], r13 = w2v[13], r14 = w2v[14], r15 = w2v[15];
#define PK2N(n, f4) \
  const half2_t n##a = {(_Float16)(-2.f * SC * (f4).x), (_Float16)(-2.f * SC * (f4).y)}; \
  const half2_t n##b = {(_Float16)(-2.f * SC * (f4).z), (_Float16)(-2.f * SC * (f4).w)}
  PK2N(q0, r0);  PK2N(q1, r1q); PK2N(q2, r2q); PK2N(q3, r3q);
  PK2N(q4, r4);  PK2N(q5, r5);  PK2N(q6, r6);  PK2N(q7, r7);
  PK2N(q8, r8);  PK2N(q9, r9);  PK2N(q10, r10); PK2N(q11, r11);
  PK2N(q12, r12); PK2N(q13, r13); PK2N(q14, r14); PK2N(q15, r15);
#undef PK2N
#define DOTQ2(P, Xq, qe, qo) \
      a##P##0 = dot2h(qe##a, bch(Xq.x), a##P##0); \
      a##P##1 = dot2h(qe##b, bch(Xq.y), a##P##1); \
      a##P##2 = dot2h(qo##a, bch(Xq.z), a##P##2); \
      a##P##3 = dot2h(qo##b, bch(Xq.w), a##P##3)
#endif

  const float base2 = SC * b2[h] + SC * rsum;
  const float w32h = w3[2 * HID + h];
  const float w32n2 = -2.f * w32h;
  const float b32 = b3[2];

  float commRA = (h < NA) ? comm_init[rA * NA + h] : 0.f;
  float commRB = (h < NA) ? comm_init[rB * NA + h] : 0.f;
  if (h < NA) commLA[h] = commRA;
  if (h < NA) commLB[h] = commRB;

  float* prowA = pre1h2 + (size_t)rA * STEPS_PER_RUN * HID;
  float* prowB = pre1h2 + (size_t)rB * STEPS_PER_RUN * HID;

  {
#pragma unroll
    for (int run = 0; run < 2; ++run) {
      const float* pr = run ? prowB : prowA;
      const float4* s0 = (const float4*)pr;
      const float4* s1 = (const float4*)(pr + 2048);
      float4* d0 = (float4*)&pbuf[run][0][0];
      float4* d1 = (float4*)&pbuf[run][1][0];
#pragma unroll
      for (int j = 0; j < 8; ++j) d0[j * 64 + h] = s0[j * 64 + h];
#pragma unroll
      for (int j = 0; j < 8; ++j) d1[j * 64 + h] = s1[j * 64 + h];
    }
  }

  for (int t = 0; t < T_STEPS; ++t) {
    float* pbA = pbuf[0][t & 1];
    float* pbB = pbuf[1][t & 1];
    int tk = (t + 2 <= T_STEPS - 1) ? t + 2 : T_STEPS - 1;
    const float4* gsA = (const float4*)(prowA + (size_t)tk * 2048);
    const float4* gsB = (const float4*)(prowB + (size_t)tk * 2048);
    float4 gA0 = gsA[0 * 64 + h], gA1 = gsA[1 * 64 + h];
    float4 gA2 = gsA[2 * 64 + h], gA3 = gsA[3 * 64 + h];
    float4 gA4 = gsA[4 * 64 + h], gA5 = gsA[5 * 64 + h];
    float4 gA6 = gsA[6 * 64 + h], gA7 = gsA[7 * 64 + h];
    float4 gB0 = gsB[0 * 64 + h], gB1 = gsB[1 * 64 + h];
    float4 gB2 = gsB[2 * 64 + h], gB3 = gsB[3 * 64 + h];
    float4 gB4 = gsB[4 * 64 + h], gB5 = gsB[5 * 64 + h];
    float4 gB6 = gsB[6 * 64 + h], gB7 = gsB[7 * 64 + h];

    float FB2A, FB2B;
    {
      const float4* cv4 = (const float4*)commLA;
      const float4* dv4 = (const float4*)commLB;
      float f0 = 0.f, f1 = 0.f, f2 = 0.f, f3 = 0.f;
      float e0 = 0.f, e1 = 0.f, e2 = 0.f, e3 = 0.f;
#pragma unroll
      for (int q = 0; q < 8; ++q) {
        float4 c = cv4[q];
        float4 d = dv4[q];
        f0 = fmaf(B2r[4 * q + 0], c.x, f0);
        e0 = fmaf(B2r[4 * q + 0], d.x, e0);
        f1 = fmaf(B2r[4 * q + 1], c.y, f1);
        e1 = fmaf(B2r[4 * q + 1], d.y, e1);
        f2 = fmaf(B2r[4 * q + 2], c.z, f2);
        e2 = fmaf(B2r[4 * q + 2], d.z, e2);
        f3 = fmaf(B2r[4 * q + 3], c.w, f3);
        e3 = fmaf(B2r[4 * q + 3], d.w, e3);
      }
      FB2A = (f0 + f1) + (f2 + f3);
      FB2B = (e0 + e1) + (e2 + e3);
    }
    const float c0sA = commRA;
    const float c0sB = commRB;
    float Q2A = 0.f, S2A = 0.f, Q2B = 0.f, S2B = 0.f;
    float EA = pbA[h] + FB2A;
    float EB = pbB[h] + FB2B;
    float* h2tA = prowA + (size_t)t * 2048;
    float* h2tB = prowB + (size_t)t * 2048;

#pragma unroll
    for (int i = 0; i < NA; ++i) {
      // --- (1) independent LDS reads issue first (latency hidden below) ---
      float pfnA = pbA[(i + 1) * 64 + h];
      float pfnB = pbB[(i + 1) * 64 + h];
      // --- (2) dual chain heads: both TRANS chains in flight together ---
      float e1A = EXPFN(EA);
      float e1B = EXPFN(EB);
      float r1A = __builtin_amdgcn_rcpf(e1A + 1.f);
      float r1B = __builtin_amdgcn_rcpf(e1B + 1.f);
      h1sA[h] = (_Float16)r1A;
      h1sB[h] = (_Float16)r1B;
      // --- (3) both broadcast round trips in flight together ---
#if HAVE_PLSWAP
      const uint4* hvA = (const uint4*)h1sA;
      const uint4* hvB = (const uint4*)h1sB;
      uint4 XA0 = hvA[hi4 + 0], XB0 = hvB[hi4 + 0];
      uint4 XA1 = hvA[hi4 + 1], XB1 = hvB[hi4 + 1];
      uint4 XA2 = hvA[hi4 + 2], XB2 = hvB[hi4 + 2];
      uint4 XA3 = hvA[hi4 + 3], XB3 = hvB[hi4 + 3];
#else
      const uint4* hvA = (const uint4*)h1sA;
      const uint4* hvB = (const uint4*)h1sB;
      uint4 XA0 = hvA[0], XB0 = hvB[0], XA1 = hvA[1], XB1 = hvB[1];
      uint4 XA2 = hvA[2], XB2 = hvB[2], XA3 = hvA[3], XB3 = hvB[3];
      uint4 XA4 = hvA[4], XB4 = hvB[4], XA5 = hvA[5], XB5 = hvB[5];
      uint4 XA6 = hvA[6], XB6 = hvB[6], XA7 = hvA[7], XB7 = hvB[7];
#endif
      // --- (4) off-chain H prep (pfn returned by now; fills read latency) ---
      float oldA = __int_as_float(__builtin_amdgcn_readlane(__float_as_int(c0sA), i + 1));
      float oldB = __int_as_float(__builtin_amdgcn_readlane(__float_as_int(c0sB), i + 1));
      float S2nA = fmaf(B2r[i + 1], oldA, S2A);
      float S2nB = fmaf(B2r[i + 1], oldB, S2B);
      float QbA = fmaf(A2r[i], b32, Q2A);
      float QbB = fmaf(A2r[i], b32, Q2B);
      float HA = pfnA + (FB2A - S2nA) + QbA;
      float HB = pfnB + (FB2B - S2nB) + QbB;
      // --- (5) dots, A/B alternated per quad ---
      float aA0 = base2, aA1 = 0.f, aA2 = 0.f, aA3 = 0.f;
      float aB0 = base2, aB1 = 0.f, aB2 = 0.f, aB3 = 0.f;
      float y2A, y2B;
#if HAVE_PLSWAP
      DOTQ(A, XA0, 0, 1); DOTQ(B, XB0, 0, 1);
      DOTQ(A, XA1, 2, 3); DOTQ(B, XB1, 2, 3);
      DOTQ(A, XA2, 4, 5); DOTQ(B, XB2, 4, 5);
      DOTQ(A, XA3, 6, 7); DOTQ(B, XB3, 6, 7);
      {
        float pA_A = aA0 + aA1, pBo_A = aA2 + aA3;
        float pA_B = aB0 + aB1, pBo_B = aB2 + aB3;
        uint2v swA = __builtin_amdgcn_permlane32_swap(
            __float_as_uint(pBo_A), __float_as_uint(pBo_A), false, false);
        uint2v swB = __builtin_amdgcn_permlane32_swap(
            __float_as_uint(pBo_B), __float_as_uint(pBo_B), false, false);
        y2A = pA_A + (hi ? __uint_as_float(swA[0]) : __uint_as_float(swA[1]));
        y2B = pA_B + (hi ? __uint_as_float(swB[0]) : __uint_as_float(swB[1]));
      }
#else
      DOTQ2(A, XA0, q0, q1);   DOTQ2(B, XB0, q0, q1);
      DOTQ2(A, XA1, q2, q3);   DOTQ2(B, XB1, q2, q3);
      DOTQ2(A, XA2, q4, q5);   DOTQ2(B, XB2, q4, q5);
      DOTQ2(A, XA3, q6, q7);   DOTQ2(B, XB3, q6, q7);
      DOTQ2(A, XA4, q8, q9);   DOTQ2(B, XB4, q8, q9);
      DOTQ2(A, XA5, q10, q11); DOTQ2(B, XB5, q10, q11);
      DOTQ2(A, XA6, q12, q13); DOTQ2(B, XB6, q12, q13);
      DOTQ2(A, XA7, q14, q15); DOTQ2(B, XB7, q14, q15);
      y2A = (aA0 + aA1) + (aA2 + aA3);
      y2B = (aB0 + aB1) + (aB2 + aB3);
#endif
      // --- (6) dual act2 ---
      float e2A = EXPFN(y2A);
      float e2B = EXPFN(y2B);
      float r2A = __builtin_amdgcn_rcpf(e2A + 1.f);
      float r2B = __builtin_amdgcn_rcpf(e2B + 1.f);
      float xrA = fmaf(w32n2, r2A, w32h);
      float xrB = fmaf(w32n2, r2B, w32h);
      // --- (7) dual interleaved butterfly ---
      float csumA = xrA, csumB = xrB;
      wave64_sum_all2(csumA, csumB);
      // --- (8) epilogue pair ---
      float h2vA = fmaf(-2.f, r2A, 1.f);
      float h2vB = fmaf(-2.f, r2B, 1.f);
      h2tA[i * 64 + h] = h2vA;
      h2tB[i * 64 + h] = h2vB;
      commRA = (h == i) ? csumA + b32 : commRA;
      commRB = (h == i) ? csumB + b32 : commRB;
      EA = fmaf(A2r[i], csumA, HA);
      EB = fmaf(A2r[i], csumB, HB);
      Q2A = fmaf(A2r[i], csumA, QbA);
      Q2B = fmaf(A2r[i], csumB, QbB);
      S2A = S2nA;
      S2B = S2nB;
    }

    if (h < NA) commLA[h] = commRA;
    if (h < NA) commLB[h] = commRB;
    float4* pdA = (float4*)pbA;
    pdA[0 * 64 + h] = gA0; pdA[1 * 64 + h] = gA1;
    pdA[2 * 64 + h] = gA2; pdA[3 * 64 + h] = gA3;
    pdA[4 * 64 + h] = gA4; pdA[5 * 64 + h] = gA5;
    pdA[6 * 64 + h] = gA6; pdA[7 * 64 + h] = gA7;
    float4* pdB = (float4*)pbB;
    pdB[0 * 64 + h] = gB0; pdB[1 * 64 + h] = gB1;
    pdB[2 * 64 + h] = gB2; pdB[3 * 64 + h] = gB3;
    pdB[4 * 64 + h] = gB4; pdB[5 * 64 + h] = gB5;
    pdB[6 * 64 + h] = gB6; pdB[7 * 64 + h] = gB7;
  }
}

// ---------------- fallback: fully fused, zero workspace (unused when ws ok) --
__global__ __launch_bounds__(64, 1) void seq_fused(
    const float* __restrict__ runs, const float* __restrict__ comm_init,
    const float* __restrict__ w1, const float* __restrict__ b1,
    const float* __restrict__ w2, const float* __restrict__ b2,
    const float* __restrict__ w3, const float* __restrict__ b3,
    float* __restrict__ out) {
  const int r = blockIdx.x;
  const int h = threadIdx.x;
  const int hb = h * 33;

  __shared__ float Asl[HID * 33];
  __shared__ float Bsl[HID * 33];
  __shared__ float commL[NA];
  __shared__ __align__(16) float h1s[HID];
  __shared__ float w1xs[XS * HID];
  __shared__ __align__(16) float xsl[96];

  for (int j = 0; j < 31; ++j) Asl[hb + j] = w1[h * DIN + 93 + j];
  Asl[hb + 31] = 0.f;
  Bsl[hb] = 0.f;
  for (int j = 1; j < 32; ++j) Bsl[hb + j] = w1[h * DIN + 92 + j];
  for (int k = 0; k < XS; ++k) w1xs[k * HID + h] = w1[h * DIN + k];

  float w2r[HID];
#pragma unroll
  for (int k = 0; k < HID; ++k) w2r[k] = w2[h * HID + k];
  const float b1h = b1[h];
  const float b2h = b2[h];
  const float w30h = w3[h], w31h = w3[HID + h], w32h = w3[2 * HID + h];
  const float b30 = b3[0], b31 = b3[1], b32 = b3[2];
  if (h < NA) commL[h] = comm_init[r * NA + h];

  const float* xbase = runs + (size_t)r * STEPS_PER_RUN * XS;
  float xa = xbase[h];
  float xb = (h < XS - 64) ? xbase[64 + h] : 0.f;
  float* outp = out + (size_t)r * STEPS_PER_RUN * 2;
  __syncthreads();

  int s = 0;
  for (int t = 0; t < T_STEPS; ++t) {
    float FB = 0.f;
#pragma unroll
    for (int j = 0; j < NA; ++j) FB = fmaf(Bsl[hb + j], commL[j], FB);
    float Q = 0.f, S = 0.f;
    for (int i = 0; i < NA; ++i, ++s) {
      int sn = s + 1; if (sn > STEPS_PER_RUN - 1) sn = STEPS_PER_RUN - 1;
      const float* xn = xbase + (size_t)sn * XS;
      xsl[h] = xa;
      if (h < XS - 64) xsl[64 + h] = xb;
      __syncthreads();
      float xa_n = xn[h];
      float xb_n = (h < XS - 64) ? xn[64 + h] : 0.f;
      float a0 = b1h, a1 = 0.f, a2 = 0.f;
#pragma unroll 4
      for (int k = 0; k < 31; ++k) {
        a0 = fmaf(xsl[3 * k],     w1xs[(3 * k) * HID + h],     a0);
        a1 = fmaf(xsl[3 * k + 1], w1xs[(3 * k + 1) * HID + h], a1);
        a2 = fmaf(xsl[3 * k + 2], w1xs[(3 * k + 2) * HID + h], a2);
      }
      float old_i = commL[i];
      S = fmaf(Bsl[hb + i], old_i, S);
      float h1 = fast_tanh(((a0 + a1) + a2) + FB + Q - S);
      h1s[h] = h1;
      __syncthreads();
      float c0 = b2h, c1 = 0.f, c2 = 0.f, c3 = 0.f;
      const float4* hv4 = (const float4*)h1s;
#pragma unroll
      for (int k4 = 0; k4 < 16; ++k4) {
        float4 hv = hv4[k4];
        c0 = fmaf(w2r[4 * k4 + 0], hv.x, c0);
        c1 = fmaf(w2r[4 * k4 + 1], hv.y, c1);
        c2 = fmaf(w2r[4 * k4 + 2], hv.z, c2);
        c3 = fmaf(w2r[4 * k4 + 3], hv.w, c3);
      }
      float h2 = fast_tanh((c0 + c1) + (c2 + c3));
      float o0 = wave64_sum_bcast(w30h * h2) + b30;
      float o1 = wave64_sum_bcast(w31h * h2) + b31;
      float c_new = wave64_sum_bcast(w32h * h2) + b32;
      if (h == 0) *(float2*)(outp + (size_t)s * 2) = make_float2(o0, o1);
      Q = fmaf(Asl[hb + i], c_new, Q);
      if (h == i) commL[h] = c_new;
      __syncthreads();
      xa = xa_n; xb = xb_n;
    }
  }
}

extern "C" void kernel_launch(void* const* d_in, const int* in_sizes, int n_in,
                              void* d_out, int out_size, void* d_ws, size_t ws_size,
                              hipStream_t stream) {
  const float* runs = (const float*)d_in[0];
  const float* comm_init = (const float*)d_in[1];
  const float* w1 = (const float*)d_in[2];
  const float* b1 = (const float*)d_in[3];
  const float* w2 = (const float*)d_in[4];
  const float* b2 = (const float*)d_in[5];
  const float* w3 = (const float*)d_in[6];
  const float* b3 = (const float*)d_in[7];
  float* out = (float*)d_out;

  if (ws_size >= WS_NEEDED) {
    float* w1T4 = (float*)d_ws;
    float* pre1 = (float*)((char*)d_ws + PRE1_OFF);
    hipLaunchKernelGGL(transpose_w1, dim3((24 * HID * 4 + 255) / 256), dim3(256), 0, stream,
                       w1, w1T4);
    hipLaunchKernelGGL(pre1_kernel, dim3(RTI_TOT / (PRE1_BATCH * 4)), dim3(256), 0, stream,
                       runs, w1T4, b1, pre1);
    hipLaunchKernelGGL(seq_kernel, dim3(R_RUNS / 2), dim3(64), 0, stream,
                       w1, w2, b2, w3, b3, comm_init, pre1);
    hipLaunchKernelGGL(out_kernel, dim3(RTI_TOT / 256), dim3(256), 0, stream,
                       pre1, w3, b3, out);
  } else {
    hipLaunchKernelGGL(seq_fused, dim3(R_RUNS), dim3(64), 0, stream,
                       runs, comm_init, w1, b1, w2, b2, w3, b3, out);
  }
}